// Round 1
// baseline (482.595 us; speedup 1.0000x reference)
//
#include <hip/hip_runtime.h>
#include <hip/hip_bf16.h>

#define NROWS 8192
#define DDIM 256
#define MARGIN_F 0.2f

#define BM 128
#define BN 128
#define BK 32
#define CSPLIT 8
#define COLS_PER_SPLIT (NROWS / CSPLIT)   // 1024
#define NCOLTILES (COLS_PER_SPLIT / BN)   // 8
#define LSTR (BM + 4)                     // padded LDS row stride (floats)

// ---------------- kernel 1: row squared norms ----------------
__global__ __launch_bounds__(256)
void sq_kernel(const float* __restrict__ E, float* __restrict__ sq) {
  const int lane = threadIdx.x & 63;
  const int row = blockIdx.x * 4 + (threadIdx.x >> 6);
  const float4 v = *(const float4*)&E[row * DDIM + lane * 4];
  float s = v.x * v.x + v.y * v.y + v.z * v.z + v.w * v.w;
#pragma unroll
  for (int o = 32; o > 0; o >>= 1) s += __shfl_down(s, o, 64);
  if (lane == 0) sq[row] = s;
}

// ---------------- kernel 2: fused dist-GEMM + hardest pos/neg mining ----------------
// block: 256 threads (16x16), tile 128x128, micro-tile 8x8 per thread.
// grid: (CSPLIT col-splits, NROWS/BM row blocks)
__global__ __launch_bounds__(256, 2)
void mine_kernel(const float* __restrict__ E, const int* __restrict__ T,
                 const float* __restrict__ sq,
                 float* __restrict__ pv, int* __restrict__ pi,
                 float* __restrict__ nv, int* __restrict__ ni) {
  __shared__ float lds_raw[2 * BK * LSTR];   // 33792 B; reused for reduction
  float* As = lds_raw;                        // [BK][LSTR], A transposed: As[k][m]
  float* Bs = lds_raw + BK * LSTR;            // [BK][LSTR]

  const int tid = threadIdx.x;
  const int tx = tid & 15;
  const int ty = tid >> 4;
  const int rowbase = blockIdx.y * BM;
  const int colbase0 = blockIdx.x * COLS_PER_SPLIT;

  float sqi[8]; int ti[8];
#pragma unroll
  for (int i = 0; i < 8; ++i) {
    sqi[i] = sq[rowbase + ty * 8 + i];
    ti[i] = T[rowbase + ty * 8 + i];
  }

  float bpv[8], bnv[8]; int bpi[8], bni[8];
#pragma unroll
  for (int i = 0; i < 8; ++i) { bpv[i] = -3e38f; bnv[i] = 3e38f; bpi[i] = 0; bni[i] = 0; }

  const int kc = (tid & 7) * 4;   // k-chunk within BK (0,4,...,28)
  const int mb = tid >> 3;        // row 0..31 within tile (4 rounds of 32)

  for (int ct = 0; ct < NCOLTILES; ++ct) {
    const int cb = colbase0 + ct * BN;
    float acc[8][8];
#pragma unroll
    for (int i = 0; i < 8; ++i)
#pragma unroll
      for (int j = 0; j < 8; ++j) acc[i][j] = 0.f;

    for (int kb = 0; kb < DDIM; kb += BK) {
      __syncthreads();
#pragma unroll
      for (int r = 0; r < 4; ++r) {
        const int m = mb + 32 * r;
        const float4 a = *(const float4*)&E[(rowbase + m) * DDIM + kb + kc];
        As[(kc + 0) * LSTR + m] = a.x;
        As[(kc + 1) * LSTR + m] = a.y;
        As[(kc + 2) * LSTR + m] = a.z;
        As[(kc + 3) * LSTR + m] = a.w;
        const float4 b = *(const float4*)&E[(cb + m) * DDIM + kb + kc];
        Bs[(kc + 0) * LSTR + m] = b.x;
        Bs[(kc + 1) * LSTR + m] = b.y;
        Bs[(kc + 2) * LSTR + m] = b.z;
        Bs[(kc + 3) * LSTR + m] = b.w;
      }
      __syncthreads();
#pragma unroll 4
      for (int k = 0; k < BK; ++k) {
        const float4 a0 = *(const float4*)&As[k * LSTR + ty * 8];
        const float4 a1 = *(const float4*)&As[k * LSTR + ty * 8 + 4];
        const float4 b0 = *(const float4*)&Bs[k * LSTR + tx * 8];
        const float4 b1 = *(const float4*)&Bs[k * LSTR + tx * 8 + 4];
        const float av[8] = {a0.x, a0.y, a0.z, a0.w, a1.x, a1.y, a1.z, a1.w};
        const float bv[8] = {b0.x, b0.y, b0.z, b0.w, b1.x, b1.y, b1.z, b1.w};
#pragma unroll
        for (int i = 0; i < 8; ++i)
#pragma unroll
          for (int j = 0; j < 8; ++j)
            acc[i][j] = fmaf(av[i], bv[j], acc[i][j]);
      }
    }

    // epilogue: dist = sq_i + sq_j - 2*dot ; online argmax(pos)/argmin(neg)
#pragma unroll
    for (int j = 0; j < 8; ++j) {
      const int c = cb + tx * 8 + j;
      const float sqj = sq[c];
      const int tj = T[c];
#pragma unroll
      for (int i = 0; i < 8; ++i) {
        const float dst = fmaf(-2.f, acc[i][j], sqi[i] + sqj);
        if (ti[i] == tj) {
          if (dst > bpv[i]) { bpv[i] = dst; bpi[i] = c; }   // strict > keeps first idx
        } else {
          if (dst < bnv[i]) { bnv[i] = dst; bni[i] = c; }
        }
      }
    }
  }

  // cross-tx reduction per row (tx ascending == column ascending, tie-break low idx)
  __syncthreads();
  float4* red = (float4*)lds_raw;   // [BM][16]
#pragma unroll
  for (int i = 0; i < 8; ++i)
    red[(ty * 8 + i) * 16 + tx] =
        make_float4(bpv[i], __int_as_float(bpi[i]), bnv[i], __int_as_float(bni[i]));
  __syncthreads();
  if (tid < BM) {
    float Pv = -3e38f, Nv = 3e38f; int Pi = 0, Ni = 0;
    for (int t = 0; t < 16; ++t) {
      const float4 v = red[tid * 16 + t];
      const int px = __float_as_int(v.y), nx = __float_as_int(v.w);
      if (v.x > Pv || (v.x == Pv && px < Pi)) { Pv = v.x; Pi = px; }
      if (v.z < Nv || (v.z == Nv && nx < Ni)) { Nv = v.z; Ni = nx; }
    }
    const int o = (rowbase + tid) * CSPLIT + blockIdx.x;
    pv[o] = Pv; pi[o] = Pi; nv[o] = Nv; ni[o] = Ni;
  }
}

// ---------------- kernel 3: combine splits, exact ap/an, losses, triplets ----------------
__global__ __launch_bounds__(256)
void finish_kernel(const float* __restrict__ E,
                   const float* __restrict__ pv, const int* __restrict__ pi,
                   const float* __restrict__ nv, const int* __restrict__ ni,
                   float* __restrict__ out, float* __restrict__ bl) {
  const int w = threadIdx.x >> 6, lane = threadIdx.x & 63;
  const int row = blockIdx.x * 4 + w;
  float Pv = -3e38f, Nv = 3e38f; int Pi = 0, Ni = 0;
#pragma unroll
  for (int s = 0; s < CSPLIT; ++s) {
    const float p = pv[row * CSPLIT + s]; const int px = pi[row * CSPLIT + s];
    if (p > Pv || (p == Pv && px < Pi)) { Pv = p; Pi = px; }
    const float n = nv[row * CSPLIT + s]; const int nx = ni[row * CSPLIT + s];
    if (n < Nv || (n == Nv && nx < Ni)) { Nv = n; Ni = nx; }
  }
  const float4 a = *(const float4*)&E[row * DDIM + lane * 4];
  const float4 p4 = *(const float4*)&E[Pi * DDIM + lane * 4];
  const float4 n4 = *(const float4*)&E[Ni * DDIM + lane * 4];
  float ap = (a.x - p4.x) * (a.x - p4.x) + (a.y - p4.y) * (a.y - p4.y)
           + (a.z - p4.z) * (a.z - p4.z) + (a.w - p4.w) * (a.w - p4.w);
  float an = (a.x - n4.x) * (a.x - n4.x) + (a.y - n4.y) * (a.y - n4.y)
           + (a.z - n4.z) * (a.z - n4.z) + (a.w - n4.w) * (a.w - n4.w);
#pragma unroll
  for (int o = 32; o > 0; o >>= 1) {
    ap += __shfl_down(ap, o, 64);
    an += __shfl_down(an, o, 64);
  }
  __shared__ float ls[4];
  if (lane == 0) {
    out[1 + row * 3 + 0] = (float)row;
    out[1 + row * 3 + 1] = (float)Pi;
    out[1 + row * 3 + 2] = (float)Ni;
    ls[w] = fmaxf(ap - an + MARGIN_F, 0.f);
  }
  __syncthreads();
  if (threadIdx.x == 0) bl[blockIdx.x] = (ls[0] + ls[1]) + (ls[2] + ls[3]);
}

// ---------------- kernel 4: deterministic mean ----------------
__global__ __launch_bounds__(256)
void sum_kernel(const float* __restrict__ bl, float* __restrict__ out) {
  __shared__ float s[256];
  float t = 0.f;
#pragma unroll
  for (int r = 0; r < (NROWS / 4) / 256; ++r) t += bl[threadIdx.x + r * 256];
  s[threadIdx.x] = t;
  __syncthreads();
  for (int o = 128; o > 0; o >>= 1) {
    if (threadIdx.x < o) s[threadIdx.x] += s[threadIdx.x + o];
    __syncthreads();
  }
  if (threadIdx.x == 0) out[0] = s[0] * (1.f / NROWS);
}

extern "C" void kernel_launch(void* const* d_in, const int* in_sizes, int n_in,
                              void* d_out, int out_size, void* d_ws, size_t ws_size,
                              hipStream_t stream) {
  const float* E = (const float*)d_in[0];
  const int* T = (const int*)d_in[1];
  float* out = (float*)d_out;

  // workspace carve-up (~1.04 MB)
  float* sq = (float*)d_ws;                       // NROWS
  float* pv = sq + NROWS;                         // NROWS*CSPLIT
  int*   pi = (int*)(pv + NROWS * CSPLIT);        // NROWS*CSPLIT
  float* nv = (float*)(pi + NROWS * CSPLIT);      // NROWS*CSPLIT
  int*   ni = (int*)(nv + NROWS * CSPLIT);        // NROWS*CSPLIT
  float* bl = (float*)(ni + NROWS * CSPLIT);      // NROWS/4

  sq_kernel<<<NROWS / 4, 256, 0, stream>>>(E, sq);
  mine_kernel<<<dim3(CSPLIT, NROWS / BM), 256, 0, stream>>>(E, T, sq, pv, pi, nv, ni);
  finish_kernel<<<NROWS / 4, 256, 0, stream>>>(E, pv, pi, nv, ni, out, bl);
  sum_kernel<<<1, 256, 0, stream>>>(bl, out);
}

// Round 2
// 165.718 us; speedup vs baseline: 2.9121x; 2.9121x over previous
//
#include <hip/hip_runtime.h>
#include <hip/hip_bf16.h>

#define NROWS 8192
#define DDIM 256
#define MARGIN_F 0.2f

#define CSPLIT 8
#define NSTR 72          // LDS row stride in halves: 32 hi | 32 lo | 8 pad

typedef _Float16 half8 __attribute__((ext_vector_type(8)));
typedef float f32x4 __attribute__((ext_vector_type(4)));
typedef int i32x4 __attribute__((ext_vector_type(4)));

// ---------------- kernel 1: row squared norms ----------------
__global__ __launch_bounds__(256)
void sq_kernel(const float* __restrict__ E, float* __restrict__ sq) {
  const int lane = threadIdx.x & 63;
  const int row = blockIdx.x * 4 + (threadIdx.x >> 6);
  const float4 v = *(const float4*)&E[row * DDIM + lane * 4];
  float s = v.x * v.x + v.y * v.y + v.z * v.z + v.w * v.w;
#pragma unroll
  for (int o = 32; o > 0; o >>= 1) s += __shfl_down(s, o, 64);
  if (lane == 0) sq[row] = s;
}

// stage 16 f32 -> 16 hi halves + 16 lo halves at S (hi) / S+32 (lo)
__device__ __forceinline__ void stage16(_Float16* S, const float* src) {
  const float4 f0 = *(const float4*)(src);
  const float4 f1 = *(const float4*)(src + 4);
  const float4 f2 = *(const float4*)(src + 8);
  const float4 f3 = *(const float4*)(src + 12);
  half8 H0, L0, H1, L1;
#define CVT(H, L, e, v) { _Float16 h = (_Float16)(v); H[e] = h; L[e] = (_Float16)((v) - (float)h); }
  CVT(H0, L0, 0, f0.x) CVT(H0, L0, 1, f0.y) CVT(H0, L0, 2, f0.z) CVT(H0, L0, 3, f0.w)
  CVT(H0, L0, 4, f1.x) CVT(H0, L0, 5, f1.y) CVT(H0, L0, 6, f1.z) CVT(H0, L0, 7, f1.w)
  CVT(H1, L1, 0, f2.x) CVT(H1, L1, 1, f2.y) CVT(H1, L1, 2, f2.z) CVT(H1, L1, 3, f2.w)
  CVT(H1, L1, 4, f3.x) CVT(H1, L1, 5, f3.y) CVT(H1, L1, 6, f3.z) CVT(H1, L1, 7, f3.w)
#undef CVT
  *(half8*)(S) = H0;
  *(half8*)(S + 8) = H1;
  *(half8*)(S + 32) = L0;
  *(half8*)(S + 40) = L1;
}

// ---------------- kernel 2: split-fp16 MFMA dist-GEMM + mining ----------------
// 256 thr = 4 waves (wi,wj in 2x2), wave tile 64(i) x 64(j), block 128x128/coltile.
// mfma(A=Ej, B=Ei): D[j][i]; C/D: i = lane&15 (+16*fi), j = (lane>>4)*4+reg (+16*jf).
__global__ __launch_bounds__(256, 2)
void mine_kernel(const float* __restrict__ E, const int* __restrict__ T,
                 const float* __restrict__ sq,
                 float* __restrict__ pv, int* __restrict__ pi,
                 float* __restrict__ nv, int* __restrict__ ni) {
  __shared__ __align__(16) _Float16 Si[128 * NSTR];
  __shared__ __align__(16) _Float16 Sj[128 * NSTR];

  const int tid = threadIdx.x;
  const int lane = tid & 63;
  const int w = tid >> 6;
  const int wi = w & 1, wj = w >> 1;
  const int l15 = lane & 15, grp = lane >> 4;
  const int rowbase = blockIdx.y * 128;
  const int colbase0 = blockIdx.x * 1024;

  const int sr = tid >> 1;          // staging row 0..127
  const int skq = (tid & 1) * 16;   // staging k-offset (halves/floats)

  float sqi[4]; int ti[4];
#pragma unroll
  for (int fi = 0; fi < 4; ++fi) {
    const int i = rowbase + wi * 64 + fi * 16 + l15;
    sqi[fi] = sq[i];
    ti[fi] = T[i];
  }

  float bpv[4], bnv[4]; int bpi[4], bni[4];
#pragma unroll
  for (int fi = 0; fi < 4; ++fi) { bpv[fi] = -3e38f; bnv[fi] = 3e38f; bpi[fi] = 0; bni[fi] = 0; }

  for (int ct = 0; ct < 8; ++ct) {
    const int cb = colbase0 + ct * 128;
    f32x4 acc[4][4];
#pragma unroll
    for (int jf = 0; jf < 4; ++jf)
#pragma unroll
      for (int fi = 0; fi < 4; ++fi) acc[jf][fi] = (f32x4){0.f, 0.f, 0.f, 0.f};

    for (int kb = 0; kb < DDIM; kb += 32) {
      __syncthreads();
      stage16(&Si[sr * NSTR + skq], &E[(rowbase + sr) * DDIM + kb + skq]);
      stage16(&Sj[sr * NSTR + skq], &E[(cb + sr) * DDIM + kb + skq]);
      __syncthreads();

      half8 ajh[4], ajl[4];
#pragma unroll
      for (int jf = 0; jf < 4; ++jf) {
        const int o = (wj * 64 + jf * 16 + l15) * NSTR + grp * 8;
        ajh[jf] = *(const half8*)&Sj[o];
        ajl[jf] = *(const half8*)&Sj[o + 32];
      }
#pragma unroll
      for (int fi = 0; fi < 4; ++fi) {
        const int o = (wi * 64 + fi * 16 + l15) * NSTR + grp * 8;
        const half8 bh = *(const half8*)&Si[o];
        const half8 bl = *(const half8*)&Si[o + 32];
#pragma unroll
        for (int jf = 0; jf < 4; ++jf)
          acc[jf][fi] = __builtin_amdgcn_mfma_f32_16x16x32_f16(ajh[jf], bh, acc[jf][fi], 0, 0, 0);
#pragma unroll
        for (int jf = 0; jf < 4; ++jf)
          acc[jf][fi] = __builtin_amdgcn_mfma_f32_16x16x32_f16(ajl[jf], bh, acc[jf][fi], 0, 0, 0);
#pragma unroll
        for (int jf = 0; jf < 4; ++jf)
          acc[jf][fi] = __builtin_amdgcn_mfma_f32_16x16x32_f16(ajh[jf], bl, acc[jf][fi], 0, 0, 0);
      }
    }

    // epilogue: dist = sqi + sqj - 2*dot; online argmax(pos)/argmin(neg)
#pragma unroll
    for (int jf = 0; jf < 4; ++jf) {
      const int jb = cb + wj * 64 + jf * 16 + grp * 4;
      const f32x4 sqj = *(const f32x4*)&sq[jb];
      const i32x4 tj = *(const i32x4*)&T[jb];
#pragma unroll
      for (int fi = 0; fi < 4; ++fi) {
#pragma unroll
        for (int r = 0; r < 4; ++r) {
          const float dst = fmaf(-2.f, acc[jf][fi][r], sqi[fi] + sqj[r]);
          const int jidx = jb + r;
          if (ti[fi] == tj[r]) {
            if (dst > bpv[fi]) { bpv[fi] = dst; bpi[fi] = jidx; }
          } else {
            if (dst < bnv[fi]) { bnv[fi] = dst; bni[fi] = jidx; }
          }
        }
      }
    }
  }

  // reduce across the 4 lane-groups (j sub-rows) with index tie-break
#pragma unroll
  for (int fi = 0; fi < 4; ++fi) {
#pragma unroll
    for (int off = 16; off <= 32; off <<= 1) {
      const float ov = __shfl_xor(bpv[fi], off, 64);
      const int oi = __shfl_xor(bpi[fi], off, 64);
      if (ov > bpv[fi] || (ov == bpv[fi] && oi < bpi[fi])) { bpv[fi] = ov; bpi[fi] = oi; }
      const float on = __shfl_xor(bnv[fi], off, 64);
      const int oni = __shfl_xor(bni[fi], off, 64);
      if (on < bnv[fi] || (on == bnv[fi] && oni < bni[fi])) { bnv[fi] = on; bni[fi] = oni; }
    }
  }

  // combine the two j-waves via LDS, then write CSPLIT partials
  __syncthreads();
  float4* scr = (float4*)Si;
  if (wj == 1 && lane < 16) {
#pragma unroll
    for (int fi = 0; fi < 4; ++fi)
      scr[wi * 64 + fi * 16 + lane] =
          make_float4(bpv[fi], __int_as_float(bpi[fi]), bnv[fi], __int_as_float(bni[fi]));
  }
  __syncthreads();
  if (wj == 0 && lane < 16) {
#pragma unroll
    for (int fi = 0; fi < 4; ++fi) {
      const float4 o = scr[wi * 64 + fi * 16 + lane];
      const int oi = __float_as_int(o.y), oni = __float_as_int(o.w);
      if (o.x > bpv[fi] || (o.x == bpv[fi] && oi < bpi[fi])) { bpv[fi] = o.x; bpi[fi] = oi; }
      if (o.z < bnv[fi] || (o.z == bnv[fi] && oni < bni[fi])) { bnv[fi] = o.z; bni[fi] = oni; }
      const int row = rowbase + wi * 64 + fi * 16 + lane;
      const int oidx = row * CSPLIT + blockIdx.x;
      pv[oidx] = bpv[fi]; pi[oidx] = bpi[fi]; nv[oidx] = bnv[fi]; ni[oidx] = bni[fi];
    }
  }
}

// ---------------- kernel 3: combine splits, exact ap/an, losses, triplets ----------------
__global__ __launch_bounds__(256)
void finish_kernel(const float* __restrict__ E,
                   const float* __restrict__ pv, const int* __restrict__ pi,
                   const float* __restrict__ nv, const int* __restrict__ ni,
                   float* __restrict__ out, float* __restrict__ bl) {
  const int w = threadIdx.x >> 6, lane = threadIdx.x & 63;
  const int row = blockIdx.x * 4 + w;
  float Pv = -3e38f, Nv = 3e38f; int Pi = 0, Ni = 0;
#pragma unroll
  for (int s = 0; s < CSPLIT; ++s) {
    const float p = pv[row * CSPLIT + s]; const int px = pi[row * CSPLIT + s];
    if (p > Pv || (p == Pv && px < Pi)) { Pv = p; Pi = px; }
    const float n = nv[row * CSPLIT + s]; const int nx = ni[row * CSPLIT + s];
    if (n < Nv || (n == Nv && nx < Ni)) { Nv = n; Ni = nx; }
  }
  const float4 a = *(const float4*)&E[row * DDIM + lane * 4];
  const float4 p4 = *(const float4*)&E[Pi * DDIM + lane * 4];
  const float4 n4 = *(const float4*)&E[Ni * DDIM + lane * 4];
  float ap = (a.x - p4.x) * (a.x - p4.x) + (a.y - p4.y) * (a.y - p4.y)
           + (a.z - p4.z) * (a.z - p4.z) + (a.w - p4.w) * (a.w - p4.w);
  float an = (a.x - n4.x) * (a.x - n4.x) + (a.y - n4.y) * (a.y - n4.y)
           + (a.z - n4.z) * (a.z - n4.z) + (a.w - n4.w) * (a.w - n4.w);
#pragma unroll
  for (int o = 32; o > 0; o >>= 1) {
    ap += __shfl_down(ap, o, 64);
    an += __shfl_down(an, o, 64);
  }
  __shared__ float ls[4];
  if (lane == 0) {
    out[1 + row * 3 + 0] = (float)row;
    out[1 + row * 3 + 1] = (float)Pi;
    out[1 + row * 3 + 2] = (float)Ni;
    ls[w] = fmaxf(ap - an + MARGIN_F, 0.f);
  }
  __syncthreads();
  if (threadIdx.x == 0) bl[blockIdx.x] = (ls[0] + ls[1]) + (ls[2] + ls[3]);
}

// ---------------- kernel 4: deterministic mean ----------------
__global__ __launch_bounds__(256)
void sum_kernel(const float* __restrict__ bl, float* __restrict__ out) {
  __shared__ float s[256];
  float t = 0.f;
#pragma unroll
  for (int r = 0; r < (NROWS / 4) / 256; ++r) t += bl[threadIdx.x + r * 256];
  s[threadIdx.x] = t;
  __syncthreads();
  for (int o = 128; o > 0; o >>= 1) {
    if (threadIdx.x < o) s[threadIdx.x] += s[threadIdx.x + o];
    __syncthreads();
  }
  if (threadIdx.x == 0) out[0] = s[0] * (1.f / NROWS);
}

extern "C" void kernel_launch(void* const* d_in, const int* in_sizes, int n_in,
                              void* d_out, int out_size, void* d_ws, size_t ws_size,
                              hipStream_t stream) {
  const float* E = (const float*)d_in[0];
  const int* T = (const int*)d_in[1];
  float* out = (float*)d_out;

  float* sq = (float*)d_ws;                       // NROWS
  float* pv = sq + NROWS;                         // NROWS*CSPLIT
  int*   pi = (int*)(pv + NROWS * CSPLIT);        // NROWS*CSPLIT
  float* nv = (float*)(pi + NROWS * CSPLIT);      // NROWS*CSPLIT
  int*   ni = (int*)(nv + NROWS * CSPLIT);        // NROWS*CSPLIT
  float* bl = (float*)(ni + NROWS * CSPLIT);      // NROWS/4

  sq_kernel<<<NROWS / 4, 256, 0, stream>>>(E, sq);
  mine_kernel<<<dim3(CSPLIT, NROWS / 128), 256, 0, stream>>>(E, T, sq, pv, pi, nv, ni);
  finish_kernel<<<NROWS / 4, 256, 0, stream>>>(E, pv, pi, nv, ni, out, bl);
  sum_kernel<<<1, 256, 0, stream>>>(bl, out);
}

// Round 3
// 137.049 us; speedup vs baseline: 3.5213x; 1.2092x over previous
//
#include <hip/hip_runtime.h>

#define NROWS 8192
#define DDIM 256
#define MARGIN_F 0.2f
#define CSPLIT 8

typedef _Float16 half8 __attribute__((ext_vector_type(8)));
typedef float f32x4 __attribute__((ext_vector_type(4)));
typedef int i32x4 __attribute__((ext_vector_type(4)));

__device__ __forceinline__ void gld16(const void* g, void* l) {
  __builtin_amdgcn_global_load_lds(
      (const __attribute__((address_space(1))) void*)g,
      (__attribute__((address_space(3))) void*)l, 16, 0, 0);
}

// ---------------- kernel 1: split fp32 -> hi/lo fp16 in MFMA-tiled layout + sq ----------------
// Tiled layout: chunk (rg, kt) = 1024B at ((rg*8+kt)*512 halves): [g 0..3][r 0..15][8 halves]
// so lane l of a wave maps to offset l*16B with r=l&15, g=l>>4.
__global__ __launch_bounds__(256)
void prep_kernel(const float* __restrict__ E, _Float16* __restrict__ Eh,
                 _Float16* __restrict__ El, float* __restrict__ sq) {
  const int t = threadIdx.x;
  const int r = t >> 4;        // row within 16-row group
  const int cs = t & 15;       // 16-col segment
  const int rg = blockIdx.x;
  const int row = rg * 16 + r;
  const float* src = &E[row * DDIM + cs * 16];
  float s = 0.f;
  half8 H[2], L[2];
#pragma unroll
  for (int h = 0; h < 2; ++h) {
    const float4 f0 = *(const float4*)(src + h * 8);
    const float4 f1 = *(const float4*)(src + h * 8 + 4);
    const float v[8] = {f0.x, f0.y, f0.z, f0.w, f1.x, f1.y, f1.z, f1.w};
#pragma unroll
    for (int e = 0; e < 8; ++e) {
      s = fmaf(v[e], v[e], s);
      const _Float16 hi = (_Float16)v[e];
      H[h][e] = hi;
      L[h][e] = (_Float16)(v[e] - (float)hi);
    }
  }
  const int kt = cs >> 1;
  const int g0 = (cs & 1) * 2;
  const int base = (rg * 8 + kt) * 512;
  *(half8*)&Eh[base + g0 * 128 + r * 8] = H[0];
  *(half8*)&Eh[base + (g0 + 1) * 128 + r * 8] = H[1];
  *(half8*)&El[base + g0 * 128 + r * 8] = L[0];
  *(half8*)&El[base + (g0 + 1) * 128 + r * 8] = L[1];
#pragma unroll
  for (int o = 8; o > 0; o >>= 1) s += __shfl_down(s, o, 16);
  if (cs == 0) sq[row] = s;
}

// ---------------- kernel 2: split-fp16 MFMA dist-GEMM + mining ----------------
// 4 waves (wi,wj in 2x2), wave tile 64x64, block 128x128 per coltile.
// LDS: 2 dbuf x 4 arrays (SiH,SiL,SjH,SjL) x 4096 halves = 64 KB, all linear chunks.
__global__ __launch_bounds__(256, 2)
void mine_kernel(const _Float16* __restrict__ Eh, const _Float16* __restrict__ El,
                 const int* __restrict__ T, const float* __restrict__ sq,
                 float* __restrict__ pv, int* __restrict__ pi,
                 float* __restrict__ nv, int* __restrict__ ni) {
  __shared__ __align__(16) _Float16 S[2][4][4096];

  const int tid = threadIdx.x;
  const int lane = tid & 63;
  const int w = tid >> 6;
  const int wi = w & 1, wj = w >> 1;
  const int l15 = lane & 15, grp = lane >> 4;
  const int rowbase = blockIdx.y * 128;
  const int colbase0 = blockIdx.x * 1024;

  // staging role: wave w stages array w (0:SiH 1:SiL 2:SjH 3:SjL), 8 chunks each
  const _Float16* srcArr = (w == 0 || w == 2) ? Eh : El;
  const bool isRowSide = (w < 2);

  float sqi[4]; int ti[4];
#pragma unroll
  for (int fi = 0; fi < 4; ++fi) {
    const int i = rowbase + wi * 64 + fi * 16 + l15;
    sqi[fi] = sq[i];
    ti[fi] = T[i];
  }

  float bpv[4], bnv[4]; int bpi[4], bni[4];
#pragma unroll
  for (int fi = 0; fi < 4; ++fi) { bpv[fi] = -3e38f; bnv[fi] = 3e38f; bpi[fi] = 0; bni[fi] = 0; }

  for (int ct = 0; ct < 8; ++ct) {
    const int cb = colbase0 + ct * 128;
    const int rb16 = (isRowSide ? rowbase : cb) >> 4;

    f32x4 acc[4][4];
#pragma unroll
    for (int jf = 0; jf < 4; ++jf)
#pragma unroll
      for (int fi = 0; fi < 4; ++fi) acc[jf][fi] = (f32x4){0.f, 0.f, 0.f, 0.f};

    // prologue: stage kt=0 into buf 0
#pragma unroll
    for (int rg = 0; rg < 8; ++rg)
      gld16(srcArr + ((rb16 + rg) * 8 + 0) * 512 + lane * 8, &S[0][w][rg * 512]);
    __syncthreads();

    int cur = 0;
    for (int kt = 0; kt < 8; ++kt) {
      if (kt < 7) {   // prefetch next K-slice into the other buffer
#pragma unroll
        for (int rg = 0; rg < 8; ++rg)
          gld16(srcArr + ((rb16 + rg) * 8 + kt + 1) * 512 + lane * 8,
                &S[cur ^ 1][w][rg * 512]);
      }
      half8 ajh[4], ajl[4];
#pragma unroll
      for (int jf = 0; jf < 4; ++jf) {
        ajh[jf] = *(const half8*)&S[cur][2][(wj * 4 + jf) * 512 + lane * 8];
        ajl[jf] = *(const half8*)&S[cur][3][(wj * 4 + jf) * 512 + lane * 8];
      }
#pragma unroll
      for (int fi = 0; fi < 4; ++fi) {
        const half8 bh = *(const half8*)&S[cur][0][(wi * 4 + fi) * 512 + lane * 8];
        const half8 bl = *(const half8*)&S[cur][1][(wi * 4 + fi) * 512 + lane * 8];
#pragma unroll
        for (int jf = 0; jf < 4; ++jf)
          acc[jf][fi] = __builtin_amdgcn_mfma_f32_16x16x32_f16(ajh[jf], bh, acc[jf][fi], 0, 0, 0);
#pragma unroll
        for (int jf = 0; jf < 4; ++jf)
          acc[jf][fi] = __builtin_amdgcn_mfma_f32_16x16x32_f16(ajl[jf], bh, acc[jf][fi], 0, 0, 0);
#pragma unroll
        for (int jf = 0; jf < 4; ++jf)
          acc[jf][fi] = __builtin_amdgcn_mfma_f32_16x16x32_f16(ajh[jf], bl, acc[jf][fi], 0, 0, 0);
      }
      __syncthreads();   // drains vmcnt (prefetch) + lgkm, then barrier
      cur ^= 1;
    }

    // epilogue: dist = sqi + sqj - 2*dot; online argmax(pos)/argmin(neg)
#pragma unroll
    for (int jf = 0; jf < 4; ++jf) {
      const int jb = cb + wj * 64 + jf * 16 + grp * 4;
      const f32x4 sqj = *(const f32x4*)&sq[jb];
      const i32x4 tj = *(const i32x4*)&T[jb];
#pragma unroll
      for (int fi = 0; fi < 4; ++fi) {
#pragma unroll
        for (int r = 0; r < 4; ++r) {
          const float dst = fmaf(-2.f, acc[jf][fi][r], sqi[fi] + sqj[r]);
          const int jidx = jb + r;
          if (ti[fi] == tj[r]) {
            if (dst > bpv[fi]) { bpv[fi] = dst; bpi[fi] = jidx; }
          } else {
            if (dst < bnv[fi]) { bnv[fi] = dst; bni[fi] = jidx; }
          }
        }
      }
    }
  }

  // reduce across the 4 lane-groups (j sub-rows), index tie-break
#pragma unroll
  for (int fi = 0; fi < 4; ++fi) {
#pragma unroll
    for (int off = 16; off <= 32; off <<= 1) {
      const float ov = __shfl_xor(bpv[fi], off, 64);
      const int oi = __shfl_xor(bpi[fi], off, 64);
      if (ov > bpv[fi] || (ov == bpv[fi] && oi < bpi[fi])) { bpv[fi] = ov; bpi[fi] = oi; }
      const float on = __shfl_xor(bnv[fi], off, 64);
      const int oni = __shfl_xor(bni[fi], off, 64);
      if (on < bnv[fi] || (on == bnv[fi] && oni < bni[fi])) { bnv[fi] = on; bni[fi] = oni; }
    }
  }

  // combine the two j-waves via LDS, then write CSPLIT partials
  __syncthreads();
  float4* scr = (float4*)&S[0][0][0];
  if (wj == 1 && lane < 16) {
#pragma unroll
    for (int fi = 0; fi < 4; ++fi)
      scr[wi * 64 + fi * 16 + lane] =
          make_float4(bpv[fi], __int_as_float(bpi[fi]), bnv[fi], __int_as_float(bni[fi]));
  }
  __syncthreads();
  if (wj == 0 && lane < 16) {
#pragma unroll
    for (int fi = 0; fi < 4; ++fi) {
      const float4 o = scr[wi * 64 + fi * 16 + lane];
      const int oi = __float_as_int(o.y), oni = __float_as_int(o.w);
      if (o.x > bpv[fi] || (o.x == bpv[fi] && oi < bpi[fi])) { bpv[fi] = o.x; bpi[fi] = oi; }
      if (o.z < bnv[fi] || (o.z == bnv[fi] && oni < bni[fi])) { bnv[fi] = o.z; bni[fi] = oni; }
      const int row = rowbase + wi * 64 + fi * 16 + lane;
      const int oidx = row * CSPLIT + blockIdx.x;
      pv[oidx] = bpv[fi]; pi[oidx] = bpi[fi]; nv[oidx] = bnv[fi]; ni[oidx] = bni[fi];
    }
  }
}

// ---------------- kernel 3: combine splits, exact ap/an, losses, triplets ----------------
__global__ __launch_bounds__(256)
void finish_kernel(const float* __restrict__ E,
                   const float* __restrict__ pv, const int* __restrict__ pi,
                   const float* __restrict__ nv, const int* __restrict__ ni,
                   float* __restrict__ out, float* __restrict__ bl) {
  const int w = threadIdx.x >> 6, lane = threadIdx.x & 63;
  const int row = blockIdx.x * 4 + w;
  float Pv = -3e38f, Nv = 3e38f; int Pi = 0, Ni = 0;
#pragma unroll
  for (int s = 0; s < CSPLIT; ++s) {
    const float p = pv[row * CSPLIT + s]; const int px = pi[row * CSPLIT + s];
    if (p > Pv || (p == Pv && px < Pi)) { Pv = p; Pi = px; }
    const float n = nv[row * CSPLIT + s]; const int nx = ni[row * CSPLIT + s];
    if (n < Nv || (n == Nv && nx < Ni)) { Nv = n; Ni = nx; }
  }
  const float4 a = *(const float4*)&E[row * DDIM + lane * 4];
  const float4 p4 = *(const float4*)&E[Pi * DDIM + lane * 4];
  const float4 n4 = *(const float4*)&E[Ni * DDIM + lane * 4];
  float ap = (a.x - p4.x) * (a.x - p4.x) + (a.y - p4.y) * (a.y - p4.y)
           + (a.z - p4.z) * (a.z - p4.z) + (a.w - p4.w) * (a.w - p4.w);
  float an = (a.x - n4.x) * (a.x - n4.x) + (a.y - n4.y) * (a.y - n4.y)
           + (a.z - n4.z) * (a.z - n4.z) + (a.w - n4.w) * (a.w - n4.w);
#pragma unroll
  for (int o = 32; o > 0; o >>= 1) {
    ap += __shfl_down(ap, o, 64);
    an += __shfl_down(an, o, 64);
  }
  __shared__ float ls[4];
  if (lane == 0) {
    out[1 + row * 3 + 0] = (float)row;
    out[1 + row * 3 + 1] = (float)Pi;
    out[1 + row * 3 + 2] = (float)Ni;
    ls[w] = fmaxf(ap - an + MARGIN_F, 0.f);
  }
  __syncthreads();
  if (threadIdx.x == 0) bl[blockIdx.x] = (ls[0] + ls[1]) + (ls[2] + ls[3]);
}

// ---------------- kernel 4: deterministic mean ----------------
__global__ __launch_bounds__(256)
void sum_kernel(const float* __restrict__ bl, float* __restrict__ out) {
  __shared__ float s[256];
  float t = 0.f;
#pragma unroll
  for (int r = 0; r < (NROWS / 4) / 256; ++r) t += bl[threadIdx.x + r * 256];
  s[threadIdx.x] = t;
  __syncthreads();
  for (int o = 128; o > 0; o >>= 1) {
    if (threadIdx.x < o) s[threadIdx.x] += s[threadIdx.x + o];
    __syncthreads();
  }
  if (threadIdx.x == 0) out[0] = s[0] * (1.f / NROWS);
}

extern "C" void kernel_launch(void* const* d_in, const int* in_sizes, int n_in,
                              void* d_out, int out_size, void* d_ws, size_t ws_size,
                              hipStream_t stream) {
  const float* E = (const float*)d_in[0];
  const int* T = (const int*)d_in[1];
  float* out = (float*)d_out;

  // workspace carve-up (~9.3 MB)
  _Float16* Eh = (_Float16*)d_ws;                     // 2M halves (4 MB)
  _Float16* El = Eh + NROWS * DDIM;                   // 4 MB
  float* sq = (float*)(El + NROWS * DDIM);            // NROWS
  float* pv = sq + NROWS;                             // NROWS*CSPLIT
  int*   pi = (int*)(pv + NROWS * CSPLIT);
  float* nv = (float*)(pi + NROWS * CSPLIT);
  int*   ni = (int*)(nv + NROWS * CSPLIT);
  float* bl = (float*)(ni + NROWS * CSPLIT);          // NROWS/4

  prep_kernel<<<NROWS / 16, 256, 0, stream>>>(E, Eh, El, sq);
  mine_kernel<<<dim3(CSPLIT, NROWS / 128), 256, 0, stream>>>(Eh, El, T, sq, pv, pi, nv, ni);
  finish_kernel<<<NROWS / 4, 256, 0, stream>>>(E, pv, pi, nv, ni, out, bl);
  sum_kernel<<<1, 256, 0, stream>>>(bl, out);
}